// Round 1
// baseline (177.869 us; speedup 1.0000x reference)
//
#include <hip/hip_runtime.h>
#include <hip/hip_bf16.h>

// Problem constants (from reference): N=3072 nodes, F=128 in-feats, H=16 hidden, O=8 out
#define NN 3072
#define FF 128
#define HH 16
#define OO 8

// ---------------------------------------------------------------------------
// Kernel 1: g[n,o] = sum_f ( sum_h relu(x[n,f]*W1[f,h]+b1[f,h]) * W2[f,h,o] + b2[f,o] )
// One block = 128 threads (thread = feature), loops over 8 nodes to amortize
// weight loads (each thread keeps its feature's weights in registers).
// ---------------------------------------------------------------------------
#define NODES_PER_BLOCK 8

__global__ __launch_bounds__(128) void gnan_g_kernel(
    const float* __restrict__ x,    // [N,F]
    const float* __restrict__ W1,   // [F,H]
    const float* __restrict__ b1,   // [F,H]
    const float* __restrict__ W2,   // [F,H,O]
    const float* __restrict__ b2,   // [F,O]
    float* __restrict__ g)          // [N,O]  (workspace)
{
    const int f  = threadIdx.x;               // 0..127  (feature)
    const int n0 = blockIdx.x * NODES_PER_BLOCK;

    // Per-feature weights into registers.
    float w1[HH], bb1[HH], w2[HH][OO], bb2[OO];
#pragma unroll
    for (int h = 0; h < HH; ++h) {
        w1[h]  = W1[f * HH + h];
        bb1[h] = b1[f * HH + h];
    }
#pragma unroll
    for (int h = 0; h < HH; ++h)
#pragma unroll
        for (int o = 0; o < OO; ++o)
            w2[h][o] = W2[(f * HH + h) * OO + o];
#pragma unroll
    for (int o = 0; o < OO; ++o) bb2[o] = b2[f * OO + o];

    __shared__ float wsum[2][OO];

    for (int ni = 0; ni < NODES_PER_BLOCK; ++ni) {
        const int n = n0 + ni;
        const float xv = x[(size_t)n * FF + f];

        float v[OO];
#pragma unroll
        for (int o = 0; o < OO; ++o) v[o] = bb2[o];
#pragma unroll
        for (int h = 0; h < HH; ++h) {
            float a = fmaxf(xv * w1[h] + bb1[h], 0.f);
#pragma unroll
            for (int o = 0; o < OO; ++o) v[o] += a * w2[h][o];
        }

        // reduce v over 128 threads (2 waves): wave shuffle, then LDS combine
#pragma unroll
        for (int o = 0; o < OO; ++o) {
#pragma unroll
            for (int off = 32; off > 0; off >>= 1)
                v[o] += __shfl_down(v[o], off);
        }
        const int lane = threadIdx.x & 63;
        const int wid  = threadIdx.x >> 6;
        if (lane == 0) {
#pragma unroll
            for (int o = 0; o < OO; ++o) wsum[wid][o] = v[o];
        }
        __syncthreads();
        if (threadIdx.x < OO) {
            g[(size_t)n * OO + threadIdx.x] =
                wsum[0][threadIdx.x] + wsum[1][threadIdx.x];
        }
        __syncthreads();  // protect wsum before next node iteration
    }
}

// ---------------------------------------------------------------------------
// Kernel 2: out[n,o] = sum_m ( sum_h relu(d[n,m]*rW1[h]+rb1[h]) * rW2[h,o]
//                              + rb2[o] ) * g[m,o]
// with d = node_distances / normalization_matrix.
// One block per row n, 256 threads split the m-dimension (12 iters each).
// ---------------------------------------------------------------------------
__global__ __launch_bounds__(256) void gnan_main_kernel(
    const float* __restrict__ nd,    // [N,N] node_distances
    const float* __restrict__ nm,    // [N,N] normalization_matrix
    const float* __restrict__ g,     // [N,O]
    const float* __restrict__ rW1,   // [H]
    const float* __restrict__ rb1,   // [H]
    const float* __restrict__ rW2,   // [H,O]
    const float* __restrict__ rb2,   // [O]
    float* __restrict__ out)         // [N,O]
{
    const int n = blockIdx.x;
    const int t = threadIdx.x;

    // rho weights: wave-uniform loads -> compiler can scalarize (SGPRs)
    float w1[HH], bb1[HH], w2[HH][OO], bb2[OO];
#pragma unroll
    for (int h = 0; h < HH; ++h) { w1[h] = rW1[h]; bb1[h] = rb1[h]; }
#pragma unroll
    for (int h = 0; h < HH; ++h)
#pragma unroll
        for (int o = 0; o < OO; ++o) w2[h][o] = rW2[h * OO + o];
#pragma unroll
    for (int o = 0; o < OO; ++o) bb2[o] = rb2[o];

    const float* __restrict__ drow = nd + (size_t)n * NN;
    const float* __restrict__ nrow = nm + (size_t)n * NN;

    float acc[OO];
#pragma unroll
    for (int o = 0; o < OO; ++o) acc[o] = 0.f;

    for (int m = t; m < NN; m += 256) {
        const float dv = __fdividef(drow[m], nrow[m]);
        const float4 g0 = *reinterpret_cast<const float4*>(g + (size_t)m * OO);
        const float4 g1 = *reinterpret_cast<const float4*>(g + (size_t)m * OO + 4);

        float a[HH];
#pragma unroll
        for (int h = 0; h < HH; ++h)
            a[h] = fmaxf(dv * w1[h] + bb1[h], 0.f);

        float v[OO];
#pragma unroll
        for (int o = 0; o < OO; ++o) v[o] = bb2[o];
#pragma unroll
        for (int h = 0; h < HH; ++h)
#pragma unroll
            for (int o = 0; o < OO; ++o)
                v[o] += a[h] * w2[h][o];

        acc[0] += v[0] * g0.x;
        acc[1] += v[1] * g0.y;
        acc[2] += v[2] * g0.z;
        acc[3] += v[3] * g0.w;
        acc[4] += v[4] * g1.x;
        acc[5] += v[5] * g1.y;
        acc[6] += v[6] * g1.z;
        acc[7] += v[7] * g1.w;
    }

    // reduce acc over 256 threads (4 waves)
#pragma unroll
    for (int o = 0; o < OO; ++o) {
#pragma unroll
        for (int off = 32; off > 0; off >>= 1)
            acc[o] += __shfl_down(acc[o], off);
    }
    __shared__ float wsum[4][OO];
    const int lane = t & 63;
    const int wid  = t >> 6;
    if (lane == 0) {
#pragma unroll
        for (int o = 0; o < OO; ++o) wsum[wid][o] = acc[o];
    }
    __syncthreads();
    if (t < OO) {
        out[(size_t)n * OO + t] =
            wsum[0][t] + wsum[1][t] + wsum[2][t] + wsum[3][t];
    }
}

// ---------------------------------------------------------------------------
// Host launcher
// Inputs (setup_inputs order):
//  0:x [N,F] f32            1:edge_index (unused, int64)
//  2:node_distances [N,N]   3:normalization_matrix [N,N]
//  4:W1 [F,H]  5:b1 [F,H]   6:W2 [F,H,O]  7:b2 [F,O]
//  8:rW1 [H]   9:rb1 [H]   10:rW2 [H,O]  11:rb2 [O]
// ---------------------------------------------------------------------------
extern "C" void kernel_launch(void* const* d_in, const int* in_sizes, int n_in,
                              void* d_out, int out_size, void* d_ws, size_t ws_size,
                              hipStream_t stream) {
    const float* x   = (const float*)d_in[0];
    const float* nd  = (const float*)d_in[2];
    const float* nm  = (const float*)d_in[3];
    const float* W1  = (const float*)d_in[4];
    const float* b1  = (const float*)d_in[5];
    const float* W2  = (const float*)d_in[6];
    const float* b2  = (const float*)d_in[7];
    const float* rW1 = (const float*)d_in[8];
    const float* rb1 = (const float*)d_in[9];
    const float* rW2 = (const float*)d_in[10];
    const float* rb2 = (const float*)d_in[11];
    float* out = (float*)d_out;

    float* g = (float*)d_ws;  // [N,O] = 96 KB scratch

    gnan_g_kernel<<<NN / NODES_PER_BLOCK, 128, 0, stream>>>(x, W1, b1, W2, b2, g);
    gnan_main_kernel<<<NN, 256, 0, stream>>>(nd, nm, g, rW1, rb1, rW2, rb2, out);
}

// Round 2
// 152.608 us; speedup vs baseline: 1.1655x; 1.1655x over previous
//
#include <hip/hip_runtime.h>
#include <hip/hip_bf16.h>
#include <math.h>

// Problem constants: N=3072 nodes, F=128 in-feats, H=16 hidden, O=8 out
#define NN 3072
#define FF 128
#define HH 16
#define OO 8

// ---------------------------------------------------------------------------
// Kernel 1: gT[o][n] = sum_f ( sum_h relu(x[n,f]*W1[f,h]+b1[f,h]) * W2[f,h,o]
//                              + b2[f,o] )
// Thread = feature; NPB nodes per block to amortize per-thread weight regs.
// Writes TRANSPOSED so the main kernel can stage LDS with a linear copy.
// ---------------------------------------------------------------------------
#define NPB 4

__global__ __launch_bounds__(128) void gnan_g_kernel(
    const float* __restrict__ x,    // [N,F]
    const float* __restrict__ W1,   // [F,H]
    const float* __restrict__ b1,   // [F,H]
    const float* __restrict__ W2,   // [F,H,O]
    const float* __restrict__ b2,   // [F,O]
    float* __restrict__ gT)         // [O][N]  (workspace, offset 0)
{
    const int f  = threadIdx.x;               // 0..127  (feature)
    const int n0 = blockIdx.x * NPB;

    float w1[HH], bb1[HH], w2[HH][OO], bb2[OO];
#pragma unroll
    for (int h = 0; h < HH; ++h) {
        w1[h]  = W1[f * HH + h];
        bb1[h] = b1[f * HH + h];
    }
#pragma unroll
    for (int h = 0; h < HH; ++h)
#pragma unroll
        for (int o = 0; o < OO; ++o)
            w2[h][o] = W2[(f * HH + h) * OO + o];
#pragma unroll
    for (int o = 0; o < OO; ++o) bb2[o] = b2[f * OO + o];

    __shared__ float wsum[2][OO];

    for (int ni = 0; ni < NPB; ++ni) {
        const int n = n0 + ni;
        const float xv = x[(size_t)n * FF + f];

        float v[OO];
#pragma unroll
        for (int o = 0; o < OO; ++o) v[o] = bb2[o];
#pragma unroll
        for (int h = 0; h < HH; ++h) {
            float a = fmaxf(xv * w1[h] + bb1[h], 0.f);
#pragma unroll
            for (int o = 0; o < OO; ++o) v[o] += a * w2[h][o];
        }

#pragma unroll
        for (int o = 0; o < OO; ++o) {
#pragma unroll
            for (int off = 32; off > 0; off >>= 1)
                v[o] += __shfl_down(v[o], off);
        }
        const int lane = threadIdx.x & 63;
        const int wid  = threadIdx.x >> 6;
        if (lane == 0) {
#pragma unroll
            for (int o = 0; o < OO; ++o) wsum[wid][o] = v[o];
        }
        __syncthreads();
        if (threadIdx.x < OO) {
            gT[threadIdx.x * NN + n] = wsum[0][threadIdx.x] + wsum[1][threadIdx.x];
        }
        __syncthreads();
    }
}

// ---------------------------------------------------------------------------
// Kernel 2: out[n,o] = sum_m v_o(d_nm) * g[m,o],  d = nd/nm.
// v_o(d) is PIECEWISE-LINEAR in d with knees t_h = -rb1[h]/rW1[h]:
//   on interval j:  v_o(d) = alpha_j[o]*d + beta_j[o]
// Tables (17 intervals x 16 floats) built per-block in LDS (cheap).
// Per-lane interval cache: fast path = 2 compares + 16 FMA per pair.
// gT staged in LDS (96 KB); block = 768 threads = 12 waves = 12 rows.
// ---------------------------------------------------------------------------
__global__ __launch_bounds__(768) void gnan_main_kernel(
    const float* __restrict__ nd,    // [N,N]
    const float* __restrict__ nm,    // [N,N]
    const float* __restrict__ gT,    // [O][N] in ws
    const float* __restrict__ rW1,   // [H]
    const float* __restrict__ rb1,   // [H]
    const float* __restrict__ rW2,   // [H,O]
    const float* __restrict__ rb2,   // [O]
    float* __restrict__ out)         // [N,O]
{
    __shared__ float gs[OO * NN];          // 96 KB staged gT
    __shared__ float Kp[HH + 2];           // -inf, sorted knees, +inf
    __shared__ float rowsA[HH + 1][16];    // per interval: alpha[8], beta[8]
    __shared__ float sk[HH];               // sorted knees (scratch)
    __shared__ int   shh[HH];              // h index at sorted position
    __shared__ float cAdd[OO];             // const contributions (rW1[h]==0)

    const int t = threadIdx.x;

    // ---- per-block table build (tiny) ----
    if (t == 0) {
        for (int h = 0; h < HH; ++h) {
            float w = rW1[h];
            sk[h]  = (w != 0.0f) ? (-rb1[h] / w) : INFINITY;
            shh[h] = h;
        }
        for (int i = 1; i < HH; ++i) {          // insertion sort (in LDS)
            float kv = sk[i]; int iv = shh[i];
            int p = i - 1;
            while (p >= 0 && sk[p] > kv) { sk[p+1]=sk[p]; shh[p+1]=shh[p]; --p; }
            sk[p+1] = kv; shh[p+1] = iv;
        }
        Kp[0] = -INFINITY;
        for (int h = 0; h < HH; ++h) Kp[h + 1] = sk[h];
        Kp[HH + 1] = INFINITY;
    }
    if (t < OO) {   // units with rW1[h]==0 contribute a constant to every beta
        float c = rb2[t];
        for (int h = 0; h < HH; ++h)
            if (rW1[h] == 0.0f) c += fmaxf(rb1[h], 0.f) * rW2[h * OO + t];
        cAdd[t] = c;
    }
    __syncthreads();
    if (t < (HH + 1) * OO) {            // 136 threads: (j,o) table entries
        const int j = t >> 3, o = t & 7;
        float alpha = 0.f, beta = 0.f;
        for (int p = 0; p < HH; ++p) {
            const int h = shh[p];
            const float w = rW1[h];
            // j = count(knee <= d); w>0 active iff p<j, w<0 active iff p>=j
            const bool active = (w > 0.f) ? (p < j) : (w < 0.f ? (p >= j) : false);
            if (active) {
                alpha += w       * rW2[h * OO + o];
                beta  += rb1[h]  * rW2[h * OO + o];
            }
        }
        rowsA[j][o]     = alpha;
        rowsA[j][8 + o] = beta + cAdd[o];
    }

    // ---- stage gT into LDS (coalesced float4 copy) ----
    {
        float4*       dst = reinterpret_cast<float4*>(gs);
        const float4* src = reinterpret_cast<const float4*>(gT);
        for (int i = t; i < OO * NN / 4; i += 768) dst[i] = src[i];
    }
    __syncthreads();

    const int wave = t >> 6;            // 0..11
    const int lane = t & 63;
    const int row  = blockIdx.x * 12 + wave;

    const float* __restrict__ drow = nd + (size_t)row * NN;
    const float* __restrict__ nrow = nm + (size_t)row * NN;

    float CA[OO], CB[OO];
    float clo = INFINITY, chi = -INFINITY;   // force miss on first pair
#pragma unroll
    for (int o = 0; o < OO; ++o) { CA[o] = 0.f; CB[o] = 0.f; }

    float acc[OO];
#pragma unroll
    for (int o = 0; o < OO; ++o) acc[o] = 0.f;

    for (int it = 0; it < NN / 128; ++it) {      // 24 iters, 2 m's per lane
        const int m0 = it * 128 + lane * 2;
        const float2 dv2 = *reinterpret_cast<const float2*>(drow + m0);
        const float2 nv2 = *reinterpret_cast<const float2*>(nrow + m0);

        float2 gv[OO];
#pragma unroll
        for (int o = 0; o < OO; ++o)
            gv[o] = *reinterpret_cast<const float2*>(&gs[o * NN + m0]);

#pragma unroll
        for (int k = 0; k < 2; ++k) {
            const float d = __fdividef(k == 0 ? dv2.x : dv2.y,
                                       k == 0 ? nv2.x : nv2.y);
            if (d < clo || d >= chi) {           // interval-cache miss (rare)
                int j = 0;
#pragma unroll
                for (int p = 0; p < HH; ++p) j += (d >= Kp[p + 1]) ? 1 : 0;
                clo = Kp[j];
                chi = Kp[j + 1];
                const float4 a0 = *reinterpret_cast<const float4*>(&rowsA[j][0]);
                const float4 a1 = *reinterpret_cast<const float4*>(&rowsA[j][4]);
                const float4 b0 = *reinterpret_cast<const float4*>(&rowsA[j][8]);
                const float4 b1 = *reinterpret_cast<const float4*>(&rowsA[j][12]);
                CA[0]=a0.x; CA[1]=a0.y; CA[2]=a0.z; CA[3]=a0.w;
                CA[4]=a1.x; CA[5]=a1.y; CA[6]=a1.z; CA[7]=a1.w;
                CB[0]=b0.x; CB[1]=b0.y; CB[2]=b0.z; CB[3]=b0.w;
                CB[4]=b1.x; CB[5]=b1.y; CB[6]=b1.z; CB[7]=b1.w;
            }
#pragma unroll
            for (int o = 0; o < OO; ++o) {
                const float g = (k == 0) ? gv[o].x : gv[o].y;
                acc[o] = fmaf(fmaf(CA[o], d, CB[o]), g, acc[o]);
            }
        }
    }

    // ---- per-wave reduction (row is wave-private) ----
#pragma unroll
    for (int o = 0; o < OO; ++o) {
#pragma unroll
        for (int off = 32; off > 0; off >>= 1)
            acc[o] += __shfl_down(acc[o], off);
    }
    if (lane == 0) {
#pragma unroll
        for (int o = 0; o < OO; ++o)
            out[(size_t)row * OO + o] = acc[o];
    }
}

// ---------------------------------------------------------------------------
// Host launcher.  ws layout: gT[8][3072] f32 = 98304 B (same footprint as
// the round-1 kernel, known to fit ws_size).
// Inputs: 0:x 1:edge_index(unused) 2:nd 3:nm 4:W1 5:b1 6:W2 7:b2
//         8:rW1 9:rb1 10:rW2 11:rb2
// ---------------------------------------------------------------------------
extern "C" void kernel_launch(void* const* d_in, const int* in_sizes, int n_in,
                              void* d_out, int out_size, void* d_ws, size_t ws_size,
                              hipStream_t stream) {
    const float* x   = (const float*)d_in[0];
    const float* nd  = (const float*)d_in[2];
    const float* nm  = (const float*)d_in[3];
    const float* W1  = (const float*)d_in[4];
    const float* b1  = (const float*)d_in[5];
    const float* W2  = (const float*)d_in[6];
    const float* b2  = (const float*)d_in[7];
    const float* rW1 = (const float*)d_in[8];
    const float* rb1 = (const float*)d_in[9];
    const float* rW2 = (const float*)d_in[10];
    const float* rb2 = (const float*)d_in[11];
    float* out = (float*)d_out;

    float* gT = (float*)d_ws;   // [O][N]

    gnan_g_kernel<<<NN / NPB, 128, 0, stream>>>(x, W1, b1, W2, b2, gT);
    gnan_main_kernel<<<NN / 12, 768, 0, stream>>>(nd, nm, gT, rW1, rb1, rW2, rb2, out);
}